// Round 2
// baseline (425.155 us; speedup 1.0000x reference)
//
#include <hip/hip_runtime.h>

// N = 8192 fixed. Output layout: [0, N) = f_self = 1 - x;
// [N, N + N*N) = f_nbr = -(x_i * A_ij * x_j), row-major fp32.
//
// Structure: one block per row i (8192 blocks x 256 threads).
// Each thread handles 8 float4 (stride blockDim) => 2048 float4 = one full
// row. All 8 A-loads issued before any store for 8-deep MLP per lane.
// x[row] is wave-uniform (scalar load); x[j] tiles are L1-resident (32 KB).
constexpr int N = 8192;
constexpr int N4 = N / 4;          // 2048 float4 per row
constexpr int PER_THREAD = 8;      // 2048 / 256

__global__ __launch_bounds__(256) void dynamics_mak_kernel(
    const float* __restrict__ x,
    const float* __restrict__ A,
    float* __restrict__ out) {
    const int row = blockIdx.x;
    const float nxi = -x[row];  // fold negation into the broadcast scalar

    const float4* __restrict__ x4 = reinterpret_cast<const float4*>(x);
    const float4* __restrict__ A4 =
        reinterpret_cast<const float4*>(A) + (size_t)row * N4;
    float4* __restrict__ o4 =
        reinterpret_cast<float4*>(out + N) + (size_t)row * N4;

    float4 a[PER_THREAD];
    float4 xj[PER_THREAD];

#pragma unroll
    for (int k = 0; k < PER_THREAD; ++k) {
        const int c = threadIdx.x + k * 256;
        a[k]  = A4[c];   // 8 independent 16B loads in flight
        xj[k] = x4[c];   // L1-hit after warm-up
    }

#pragma unroll
    for (int k = 0; k < PER_THREAD; ++k) {
        const int c = threadIdx.x + k * 256;
        float4 r;
        r.x = nxi * a[k].x * xj[k].x;
        r.y = nxi * a[k].y * xj[k].y;
        r.z = nxi * a[k].z * xj[k].z;
        r.w = nxi * a[k].w * xj[k].w;
        o4[c] = r;  // out+N is 32 KB offset -> 16 B aligned
    }

    // f_self = 1 - x: block 0 writes all 8192 floats (32 KB, negligible)
    if (row == 0) {
#pragma unroll
        for (int k = 0; k < PER_THREAD; ++k) {
            const int c = threadIdx.x + k * 256;
            const float4 xv = x4[c];
            float4 s;
            s.x = 1.0f - xv.x;
            s.y = 1.0f - xv.y;
            s.z = 1.0f - xv.z;
            s.w = 1.0f - xv.w;
            reinterpret_cast<float4*>(out)[c] = s;
        }
    }
}

extern "C" void kernel_launch(void* const* d_in, const int* in_sizes, int n_in,
                              void* d_out, int out_size, void* d_ws, size_t ws_size,
                              hipStream_t stream) {
    // setup_inputs order: t (scalar, unused), x [N], A [N*N]
    const float* x = reinterpret_cast<const float*>(d_in[1]);
    const float* A = reinterpret_cast<const float*>(d_in[2]);
    float* out = reinterpret_cast<float*>(d_out);

    dynamics_mak_kernel<<<N, 256, 0, stream>>>(x, A, out);
}